// Round 12
// baseline (100.616 us; speedup 1.0000x reference)
//
#include <hip/hip_runtime.h>

typedef unsigned short u16;
typedef unsigned int u32;
typedef __attribute__((ext_vector_type(8))) short bf16x8;
typedef __attribute__((ext_vector_type(4))) float f32x4;
typedef __attribute__((ext_vector_type(4))) unsigned short u16x4;

#define DEVI __device__ __forceinline__

constexpr float L2GAMMA = -0.15200309344504997f; // log2(0.9)
constexpr float INV_SQRT_H = 0.0625f;            // 1/sqrt(256)

DEVI u16 f2bf(float x) {
  union { float f; unsigned u; } v; v.f = x;
  unsigned r = v.u + 0x7FFFu + ((v.u >> 16) & 1u);
  return (u16)(r >> 16);
}

// ---- kernel 0a: x fp32 -> bf16 -------------------------------------------
__global__ void cvt_x_kernel(const float4* __restrict__ src, u16x4* __restrict__ dst, int n4) {
  int stride = gridDim.x * blockDim.x;
  for (int i = blockIdx.x * blockDim.x + threadIdx.x; i < n4; i += stride) {
    float4 v = src[i];
    u16x4 o; o.x = f2bf(v.x); o.y = f2bf(v.y); o.z = f2bf(v.z); o.w = f2bf(v.w);
    dst[i] = o;
  }
}

// ---- kernel 0b: W_Q|W_K|W_V (each 256x1024 fp32) -> Wb[768][1024] bf16 ---
__global__ void cvt_w_kernel(const float4* __restrict__ wq, const float4* __restrict__ wk,
                             const float4* __restrict__ wv, u16x4* __restrict__ dst) {
  int i = blockIdx.x * blockDim.x + threadIdx.x; // 0..196607
  int w = i >> 16, off = i & 65535;
  const float4* s = (w == 0) ? wq : ((w == 1) ? wk : wv);
  float4 v = s[off];
  u16x4 o; o.x = f2bf(v.x); o.y = f2bf(v.y); o.z = f2bf(v.z); o.w = f2bf(v.w);
  dst[(w << 16) + off] = o;
}

// ---- kernel 1: QKV GEMM  C[16384x768] = Xb[16384x1024] * Wb^T ------------
// BM=256 BN=192 BK=64, 512 thr (8 waves 2Mx4N, wave out 128x48),
// grid 256 = 1 WG/CU exact, XCD-chunked (8 m-panels x 4 n per XCD).
// Reg-staged A and B (T14): loads for tile t+1 issued at TOP of iter t,
// ds_writes AFTER the 48 MFMAs; one __syncthreads per iter.
// LDS rows 64 u16 = 128 B = 8 x 16B slots; phys slot = j ^ (row&7).
// Bank math: byte = row*128 + phys*16 -> row drops out of bank index;
// phys spans 8 distinct slots (x2) per 16-lane group on BOTH writes and
// reads -> 2-way everywhere = free (m136).
// A coverage: 4 rounds x 512 = 2048 granules = 256x64/8. B: 3 FULL rounds
// x 512 = 1536 = 192x64/8 (R11 bug: round 2 was half-gated -> NaN).
__global__ __launch_bounds__(512, 1) void qkv_gemm_kernel(const u16* __restrict__ Xb, const u16* __restrict__ Wb,
                                                          u16* __restrict__ Qb, u16* __restrict__ Kb,
                                                          u16* __restrict__ Vt) {
  __shared__ u16 Al[2][256 * 64];   // 2 x 32 KB
  __shared__ u16 Bl[2][192 * 64];   // 2 x 24 KB
  const int bid = blockIdx.x;       // 0..255
  const int xcd = bid & 7, seq = bid >> 3;
  const int m0 = (xcd * 8 + (seq >> 2)) * 256;
  const int n0 = (seq & 3) * 192;
  const int tid = threadIdx.x;
  const int wid = tid >> 6, lane = tid & 63;
  const int wm = wid >> 2, wn = wid & 3;     // 2M x 4N
  const int lrow = lane & 15, lkg = lane >> 4;

  // A stage: rounds q=0..3, j = q*2 + (tid>>8), row = tid&255
  const int a_row = tid & 255;
  const int a_jbase = tid >> 8;
  // B stage: rounds q=0..2 (ALL full): L = q*512+tid, row = L%192, j = L/192
  uint4 ar[4], br[3];

#define LOADA(T) do { \
  _Pragma("unroll") for (int q_ = 0; q_ < 4; ++q_) { \
    const int j_ = q_ * 2 + a_jbase; \
    ar[q_] = *(const uint4*)(const void*)(Xb + (size_t)(m0 + a_row) * 1024 + (T) * 64 + j_ * 8); } \
} while (0)

#define LOADB(T) do { \
  _Pragma("unroll") for (int q_ = 0; q_ < 3; ++q_) { \
    const int L_ = q_ * 512 + tid; \
    const int row_ = L_ % 192, j_ = L_ / 192; \
    br[q_] = *(const uint4*)(const void*)(Wb + (size_t)(n0 + row_) * 1024 + (T) * 64 + j_ * 8); } \
} while (0)

#define WRITEA(P) do { \
  _Pragma("unroll") for (int q_ = 0; q_ < 4; ++q_) { \
    const int j_ = q_ * 2 + a_jbase; \
    *(uint4*)&Al[P][a_row * 64 + ((j_ ^ (a_row & 7)) << 3)] = ar[q_]; } \
} while (0)

#define WRITEB(P) do { \
  _Pragma("unroll") for (int q_ = 0; q_ < 3; ++q_) { \
    const int L_ = q_ * 512 + tid; \
    const int row_ = L_ % 192, j_ = L_ / 192; \
    *(uint4*)&Bl[P][row_ * 64 + ((j_ ^ (row_ & 7)) << 3)] = br[q_]; } \
} while (0)

#define PHASE(C, P) do { \
  bf16x8 af_[8], bf_[3]; \
  _Pragma("unroll") for (int mf = 0; mf < 8; ++mf) { \
    const int r_ = wm * 128 + mf * 16 + lrow; \
    af_[mf] = *(const bf16x8*)&Al[P][r_ * 64 + ((((C) * 4 + lkg) ^ (r_ & 7)) << 3)]; } \
  _Pragma("unroll") for (int nf = 0; nf < 3; ++nf) { \
    const int r_ = wn * 48 + nf * 16 + lrow; \
    bf_[nf] = *(const bf16x8*)&Bl[P][r_ * 64 + ((((C) * 4 + lkg) ^ (r_ & 7)) << 3)]; } \
  __builtin_amdgcn_s_setprio(1); \
  _Pragma("unroll") for (int mf = 0; mf < 8; ++mf) \
    _Pragma("unroll") for (int nf = 0; nf < 3; ++nf) \
      acc[mf][nf] = __builtin_amdgcn_mfma_f32_16x16x32_bf16(af_[mf], bf_[nf], acc[mf][nf], 0, 0, 0); \
  __builtin_amdgcn_s_setprio(0); \
} while (0)

  f32x4 acc[8][3] = {};

  // ---- prologue: tile 0 ----
  LOADA(0); LOADB(0);
  WRITEA(0); WRITEB(0);
  __syncthreads();

  for (int t = 0; t < 16; ++t) {
    const int p = t & 1;
    if (t < 15) { LOADA(t + 1); LOADB(t + 1); }   // issue-early (T14)
    __builtin_amdgcn_sched_barrier(0);            // keep loads above compute
    PHASE(0, p);
    PHASE(1, p);
    __builtin_amdgcn_sched_barrier(0);
    if (t < 15) {
      WRITEA(p ^ 1); WRITEB(p ^ 1);               // write-late
      __syncthreads();
    }
  }

  // ---- epilogue: cols 0..255 -> Q, 256..511 -> K, 512..767 -> V^T ----
#pragma unroll
  for (int mf = 0; mf < 8; ++mf)
#pragma unroll
    for (int nf = 0; nf < 3; ++nf) {
      const int gm = m0 + wm * 128 + mf * 16 + lkg * 4;
      const int c = n0 + wn * 48 + nf * 16 + lrow;
      if (c < 512) {
        u16* Dst = (c < 256) ? Qb : Kb;
        const int cc = c & 255;
#pragma unroll
        for (int r = 0; r < 4; ++r) Dst[(size_t)(gm + r) * 256 + cc] = f2bf(acc[mf][nf][r]);
      } else {
        const int h = c - 512;
        const int bb = gm >> 12, l = gm & 4095;
        u16x4 pk;
        pk.x = f2bf(acc[mf][nf][0]); pk.y = f2bf(acc[mf][nf][1]);
        pk.z = f2bf(acc[mf][nf][2]); pk.w = f2bf(acc[mf][nf][3]);
        *(u16x4*)&Vt[((size_t)bb * 256 + h) * 4096 + l] = pk;
      }
    }
}

// ---- kernel 2: WINDOWED decay attention ----------------------------------
// gamma^320 ~ 2.5e-15 => keys older than the aligned 256..319 window are
// numerically zero in fp32. QB=32 rows/WG, KB=64, 4 waves (256 thr).
__global__ __launch_bounds__(256) void attn_kernel(const u16* __restrict__ Qb, const u16* __restrict__ Kb,
                                                   const u16* __restrict__ Vt, float* __restrict__ out) {
  __shared__ u16 Plds[32 * 72];
  const int raw = blockIdx.x;                 // 0..511
  const int aid = (raw & 7) * 64 + (raw >> 3);  // XCD-chunked
  const int b = aid >> 7;                     // 0..3
  const int qt = aid & 127;                   // 0..127
  const int qb = qt * 32;
  const int tid = threadIdx.x;
  const int wid = tid >> 6, lane = tid & 63;
  const int lrow = lane & 15, lkg = lane >> 4, lk = lkg * 8;
  const size_t bQK = (size_t)b * 4096 * 256;

  bf16x8 qf[2][8];
#pragma unroll
  for (int mf = 0; mf < 2; ++mf) {
    const u16* Qrow = Qb + bQK + (size_t)(qb + mf * 16 + lrow) * 256;
#pragma unroll
    for (int kf = 0; kf < 8; ++kf) qf[mf][kf] = *(const bf16x8*)&Qrow[kf * 32 + lk];
  }

  int kstart = qb - 256; if (kstart < 0) kstart = 0; kstart &= ~63;
  const int njt = (qb + 32 - kstart + 63) >> 6;

  f32x4 oacc[2][4] = {};

  for (int jt = 0; jt < njt; ++jt) {
    const int kb = kstart + jt * 64;
    f32x4 s[2] = {};
    const u16* Krow = Kb + bQK + (size_t)(kb + wid * 16 + lrow) * 256;
#pragma unroll
    for (int kf = 0; kf < 8; ++kf) {
      const bf16x8 kfr = *(const bf16x8*)&Krow[kf * 32 + lk];
      s[0] = __builtin_amdgcn_mfma_f32_16x16x32_bf16(qf[0][kf], kfr, s[0], 0, 0, 0);
      s[1] = __builtin_amdgcn_mfma_f32_16x16x32_bf16(qf[1][kf], kfr, s[1], 0, 0, 0);
    }
    const int kg = kb + wid * 16 + lrow;
#pragma unroll
    for (int mf = 0; mf < 2; ++mf) {
      const int qg = qb + mf * 16 + lkg * 4;
#pragma unroll
      for (int r = 0; r < 4; ++r) {
        const int d = qg + r - kg;
        const float pv = (d >= 0) ? s[mf][r] * exp2f((float)d * L2GAMMA) * INV_SQRT_H : 0.0f;
        Plds[(mf * 16 + lkg * 4 + r) * 72 + wid * 16 + lrow] = f2bf(pv);
      }
    }
    __syncthreads();
#pragma unroll
    for (int ks = 0; ks < 2; ++ks) {
      bf16x8 pa[2];
      pa[0] = *(const bf16x8*)&Plds[(lrow) * 72 + ks * 32 + lk];
      pa[1] = *(const bf16x8*)&Plds[(16 + lrow) * 72 + ks * 32 + lk];
#pragma unroll
      for (int nf = 0; nf < 4; ++nf) {
        const bf16x8 vb = *(const bf16x8*)&Vt[((size_t)b * 256 + wid * 64 + nf * 16 + lrow) * 4096 + kb + ks * 32 + lk];
        oacc[0][nf] = __builtin_amdgcn_mfma_f32_16x16x32_bf16(pa[0], vb, oacc[0][nf], 0, 0, 0);
        oacc[1][nf] = __builtin_amdgcn_mfma_f32_16x16x32_bf16(pa[1], vb, oacc[1][nf], 0, 0, 0);
      }
    }
    __syncthreads();
  }

#pragma unroll
  for (int mf = 0; mf < 2; ++mf) {
    float* obase = out + ((size_t)b * 4096 + qb + mf * 16 + lkg * 4) * 256 + wid * 64 + lrow;
#pragma unroll
    for (int nf = 0; nf < 4; ++nf)
#pragma unroll
      for (int r = 0; r < 4; ++r)
        obase[(size_t)r * 256 + nf * 16] = oacc[mf][nf][r];
  }
}

extern "C" void kernel_launch(void* const* d_in, const int* in_sizes, int n_in,
                              void* d_out, int out_size, void* d_ws, size_t ws_size,
                              hipStream_t stream) {
  const float* x  = (const float*)d_in[0];
  const float* wq = (const float*)d_in[1];
  const float* wk = (const float*)d_in[2];
  const float* wv = (const float*)d_in[3];
  float* out = (float*)d_out;
  char* ws = (char*)d_ws;
  u16* Xb = (u16*)(ws);                          // 16384*1024*2 = 33,554,432
  u16* Wb = (u16*)(ws + (size_t)33554432);       //   768*1024*2 =  1,572,864
  u16* Qb = (u16*)(ws + (size_t)35127296);       // 16384*256*2  =  8,388,608
  u16* Kb = (u16*)(ws + (size_t)43515904);       //  8,388,608
  u16* Vt = (u16*)(ws + (size_t)51904512);       //  8,388,608  (end 60,293,120)

  hipLaunchKernelGGL(cvt_x_kernel, dim3(2048), dim3(256), 0, stream,
                     (const float4*)x, (u16x4*)Xb, 4194304);
  hipLaunchKernelGGL(cvt_w_kernel, dim3(768), dim3(256), 0, stream,
                     (const float4*)wq, (const float4*)wk, (const float4*)wv, (u16x4*)Wb);
  hipLaunchKernelGGL(qkv_gemm_kernel, dim3(256), dim3(512), 0, stream, Xb, Wb, Qb, Kb, Vt);
  hipLaunchKernelGGL(attn_kernel, dim3(512), dim3(256), 0, stream, Qb, Kb, Vt, out);
}

// Round 14
// 82.698 us; speedup vs baseline: 1.2167x; 1.2167x over previous
//
#include <hip/hip_runtime.h>

typedef unsigned short u16;
typedef unsigned int u32;
typedef __attribute__((ext_vector_type(8))) short bf16x8;
typedef __attribute__((ext_vector_type(4))) float f32x4;
typedef __attribute__((ext_vector_type(4))) unsigned short u16x4;

#define DEVI __device__ __forceinline__
#define AS1 __attribute__((address_space(1)))
#define AS3 __attribute__((address_space(3)))

constexpr float L2GAMMA = -0.15200309344504997f; // log2(0.9)
constexpr float INV_SQRT_H = 0.0625f;            // 1/sqrt(256)

DEVI u16 f2bf(float x) {
  union { float f; unsigned u; } v; v.f = x;
  unsigned r = v.u + 0x7FFFu + ((v.u >> 16) & 1u);
  return (u16)(r >> 16);
}

// ---- kernel 0a: x fp32 -> bf16 -------------------------------------------
__global__ void cvt_x_kernel(const float4* __restrict__ src, u16x4* __restrict__ dst, int n4) {
  int stride = gridDim.x * blockDim.x;
  for (int i = blockIdx.x * blockDim.x + threadIdx.x; i < n4; i += stride) {
    float4 v = src[i];
    u16x4 o; o.x = f2bf(v.x); o.y = f2bf(v.y); o.z = f2bf(v.z); o.w = f2bf(v.w);
    dst[i] = o;
  }
}

// ---- kernel 0b: W_Q|W_K|W_V (each 256x1024 fp32) -> Wb[768][1024] bf16 ---
__global__ void cvt_w_kernel(const float4* __restrict__ wq, const float4* __restrict__ wk,
                             const float4* __restrict__ wv, u16x4* __restrict__ dst) {
  int i = blockIdx.x * blockDim.x + threadIdx.x; // 0..196607
  int w = i >> 16, off = i & 65535;
  const float4* s = (w == 0) ? wq : ((w == 1) ? wk : wv);
  float4 v = s[off];
  u16x4 o; o.x = f2bf(v.x); o.y = f2bf(v.y); o.z = f2bf(v.z); o.w = f2bf(v.w);
  dst[(w << 16) + off] = o;
}

// ---- kernel 1: QKV GEMM, genuine 8-phase template (m201 port) ------------
// C[16384x768] = Xb * Wb^T.  BM=256 BN=192 BK=64, 8 waves 2Mx4N (wave out
// 128x48), grid 256 = 1 WG/CU, XCD-chunked.
// REGION MAP (R13 bugfix): A round RB holds rows RB*64..+63; the MFMA
// phases read by m-half across BOTH wm blocks:
//   MH=0 reads rows 0-63 & 128-191  = rounds {0,2}
//   MH=1 reads rows 64-127 & 192-255 = rounds {1,3}
// R13 staged {0,1}/{2,3} -> wrote round 1 while ph3/4 read it (race).
// Corrected issue points (each region >=1 barrier after its last read):
//  prev ph7: buf1 rounds {0,2} <- t1'      (buf1 MH0 free after ph6)
//  ph1:      buf1 rounds {1,3} + B <- t1   (free after prev ph8)
//  ph3:      buf0 rounds {0,2} <- tn       (free after ph2)
//  ph5:      buf0 rounds {1,3} <- tn       (free after ph4)
//  ph6:      buf0 B <- tn                  (free after ph4)
// vmcnt(2) ONLY at ph4/ph8 (FIFO: 7 oldest land = the buffer about to be
// read; 2 stay in flight). Never vmcnt(0) until the tail.
// Swizzle (R12-verified 0-conflict): phys 16B-slot = j ^ (row&7), via
// pre-swizzled GLOBAL source + linear gload_lds dest (rule 21).
__global__ __launch_bounds__(512, 1) void qkv_gemm_kernel(const u16* __restrict__ Xb, const u16* __restrict__ Wb,
                                                          u16* __restrict__ Qb, u16* __restrict__ Kb,
                                                          u16* __restrict__ Vt) {
  __shared__ u16 Al[2][256 * 64];   // 2 x 32 KB
  __shared__ u16 Bl[2][192 * 64];   // 2 x 24 KB
  const int bid = blockIdx.x;       // 0..255
  const int xcd = bid & 7, seq = bid >> 3;
  const int m0 = (xcd * 8 + (seq >> 2)) * 256;
  const int n0 = (seq & 3) * 192;
  const int tid = threadIdx.x;
  const int wid = tid >> 6;
  const int lane = tid & 63;
  const int wm = wid >> 2, wn = wid & 3;     // 2M x 4N
  const int lrow = lane & 15, lkg = lane >> 4;

#define STAGE_A(P, RB, T) do { \
  const int row_ = (RB) * 64 + (tid >> 3); \
  const u16* g_ = Xb + (size_t)(m0 + row_) * 1024 + (T) * 64 + (((tid & 7) ^ ((tid >> 3) & 7)) << 3); \
  __builtin_amdgcn_global_load_lds((const AS1 void*)g_, (AS3 void*)&Al[P][(RB) * 4096 + tid * 8], 16, 0, 0); \
} while (0)

#define STAGE_B(P, Q, T) do { \
  const int row_ = (Q) * 64 + (tid >> 3); \
  const u16* g_ = Wb + (size_t)(n0 + row_) * 1024 + (T) * 64 + (((tid & 7) ^ ((tid >> 3) & 7)) << 3); \
  __builtin_amdgcn_global_load_lds((const AS1 void*)g_, (AS3 void*)&Bl[P][(Q) * 4096 + tid * 8], 16, 0, 0); \
} while (0)

#define PHASE(P, MH, KK, ISSUES, TAIL) do { \
  bf16x8 af_[4]; bf16x8 bf_[3]; \
  _Pragma("unroll") for (int mf = 0; mf < 4; ++mf) { \
    const int r_ = wm * 128 + (MH) * 64 + mf * 16 + lrow; \
    af_[mf] = *(const bf16x8*)&Al[P][r_ * 64 + ((((KK) * 4 + lkg) ^ (r_ & 7)) << 3)]; } \
  _Pragma("unroll") for (int nf = 0; nf < 3; ++nf) { \
    const int r_ = wn * 48 + nf * 16 + lrow; \
    bf_[nf] = *(const bf16x8*)&Bl[P][r_ * 64 + ((((KK) * 4 + lkg) ^ (r_ & 7)) << 3)]; } \
  ISSUES; \
  __builtin_amdgcn_s_barrier(); \
  asm volatile("s_waitcnt lgkmcnt(0)" ::: "memory"); \
  __builtin_amdgcn_sched_barrier(0); \
  __builtin_amdgcn_s_setprio(1); \
  _Pragma("unroll") for (int mf = 0; mf < 4; ++mf) \
    _Pragma("unroll") for (int nf = 0; nf < 3; ++nf) \
      acc[(MH) * 4 + mf][nf] = __builtin_amdgcn_mfma_f32_16x16x32_bf16(af_[mf], bf_[nf], acc[(MH) * 4 + mf][nf], 0, 0, 0); \
  __builtin_amdgcn_s_setprio(0); \
  TAIL; \
  __builtin_amdgcn_s_barrier(); \
} while (0)

  f32x4 acc[8][3] = {};

  // ---- prologue: tile0 -> buf0 (7 rounds) + buf1 MH0 rounds {0,2} <- t1 ----
  STAGE_A(0, 0, 0); STAGE_A(0, 1, 0); STAGE_A(0, 2, 0); STAGE_A(0, 3, 0);
  STAGE_B(0, 0, 0); STAGE_B(0, 1, 0); STAGE_B(0, 2, 0);
  STAGE_A(1, 0, 1); STAGE_A(1, 2, 1);
  asm volatile("s_waitcnt vmcnt(2)" ::: "memory");   // tile0's 7 landed
  __builtin_amdgcn_s_barrier();

  for (int i = 0; i < 7; ++i) {
    const int t1 = 2 * i + 1;
    const int tn = 2 * i + 2;
    PHASE(0, 0, 0, { STAGE_A(1, 1, t1); STAGE_A(1, 3, t1);
                     STAGE_B(1, 0, t1); STAGE_B(1, 1, t1); STAGE_B(1, 2, t1); }, );
    PHASE(0, 0, 1, , );
    PHASE(0, 1, 0, { STAGE_A(0, 0, tn); STAGE_A(0, 2, tn); }, );
    PHASE(0, 1, 1, , asm volatile("s_waitcnt vmcnt(2)" ::: "memory"));
    PHASE(1, 0, 0, { STAGE_A(0, 1, tn); STAGE_A(0, 3, tn); }, );
    PHASE(1, 0, 1, { STAGE_B(0, 0, tn); STAGE_B(0, 1, tn); STAGE_B(0, 2, tn); }, );
    PHASE(1, 1, 0, { STAGE_A(1, 0, tn + 1); STAGE_A(1, 2, tn + 1); }, );
    PHASE(1, 1, 1, , asm volatile("s_waitcnt vmcnt(2)" ::: "memory"));
  }
  // ---- tail iteration: tiles 14 (buf0), 15 (buf1); finish staging 15 ----
  PHASE(0, 0, 0, { STAGE_A(1, 1, 15); STAGE_A(1, 3, 15);
                   STAGE_B(1, 0, 15); STAGE_B(1, 1, 15); STAGE_B(1, 2, 15); }, );
  PHASE(0, 0, 1, , );
  PHASE(0, 1, 0, , );
  PHASE(0, 1, 1, , asm volatile("s_waitcnt vmcnt(0)" ::: "memory"));
  PHASE(1, 0, 0, , );
  PHASE(1, 0, 1, , );
  PHASE(1, 1, 0, , );
  PHASE(1, 1, 1, , );

  // ---- epilogue: cols 0..255 -> Q, 256..511 -> K, 512..767 -> V^T ----
#pragma unroll
  for (int mf = 0; mf < 8; ++mf)
#pragma unroll
    for (int nf = 0; nf < 3; ++nf) {
      const int gm = m0 + wm * 128 + mf * 16 + lkg * 4;
      const int c = n0 + wn * 48 + nf * 16 + lrow;
      if (c < 512) {
        u16* Dst = (c < 256) ? Qb : Kb;
        const int cc = c & 255;
#pragma unroll
        for (int r = 0; r < 4; ++r) Dst[(size_t)(gm + r) * 256 + cc] = f2bf(acc[mf][nf][r]);
      } else {
        const int h = c - 512;
        const int bb = gm >> 12, l = gm & 4095;
        u16x4 pk;
        pk.x = f2bf(acc[mf][nf][0]); pk.y = f2bf(acc[mf][nf][1]);
        pk.z = f2bf(acc[mf][nf][2]); pk.w = f2bf(acc[mf][nf][3]);
        *(u16x4*)&Vt[((size_t)bb * 256 + h) * 4096 + l] = pk;
      }
    }
}

// ---- kernel 2: WINDOWED decay attention ----------------------------------
// gamma^320 ~ 2.5e-15 => keys older than the aligned 256..319 window are
// numerically zero in fp32. QB=32 rows/WG, KB=64, 4 waves (256 thr).
__global__ __launch_bounds__(256) void attn_kernel(const u16* __restrict__ Qb, const u16* __restrict__ Kb,
                                                   const u16* __restrict__ Vt, float* __restrict__ out) {
  __shared__ u16 Plds[32 * 72];
  const int raw = blockIdx.x;                 // 0..511
  const int aid = (raw & 7) * 64 + (raw >> 3);  // XCD-chunked
  const int b = aid >> 7;                     // 0..3
  const int qt = aid & 127;                   // 0..127
  const int qb = qt * 32;
  const int tid = threadIdx.x;
  const int wid = tid >> 6, lane = tid & 63;
  const int lrow = lane & 15, lkg = lane >> 4, lk = lkg * 8;
  const size_t bQK = (size_t)b * 4096 * 256;

  bf16x8 qf[2][8];
#pragma unroll
  for (int mf = 0; mf < 2; ++mf) {
    const u16* Qrow = Qb + bQK + (size_t)(qb + mf * 16 + lrow) * 256;
#pragma unroll
    for (int kf = 0; kf < 8; ++kf) qf[mf][kf] = *(const bf16x8*)&Qrow[kf * 32 + lk];
  }

  int kstart = qb - 256; if (kstart < 0) kstart = 0; kstart &= ~63;
  const int njt = (qb + 32 - kstart + 63) >> 6;

  f32x4 oacc[2][4] = {};

  for (int jt = 0; jt < njt; ++jt) {
    const int kb = kstart + jt * 64;
    f32x4 s[2] = {};
    const u16* Krow = Kb + bQK + (size_t)(kb + wid * 16 + lrow) * 256;
#pragma unroll
    for (int kf = 0; kf < 8; ++kf) {
      const bf16x8 kfr = *(const bf16x8*)&Krow[kf * 32 + lk];
      s[0] = __builtin_amdgcn_mfma_f32_16x16x32_bf16(qf[0][kf], kfr, s[0], 0, 0, 0);
      s[1] = __builtin_amdgcn_mfma_f32_16x16x32_bf16(qf[1][kf], kfr, s[1], 0, 0, 0);
    }
    const int kg = kb + wid * 16 + lrow;
#pragma unroll
    for (int mf = 0; mf < 2; ++mf) {
      const int qg = qb + mf * 16 + lkg * 4;
#pragma unroll
      for (int r = 0; r < 4; ++r) {
        const int d = qg + r - kg;
        const float pv = (d >= 0) ? s[mf][r] * exp2f((float)d * L2GAMMA) * INV_SQRT_H : 0.0f;
        Plds[(mf * 16 + lkg * 4 + r) * 72 + wid * 16 + lrow] = f2bf(pv);
      }
    }
    __syncthreads();
#pragma unroll
    for (int ks = 0; ks < 2; ++ks) {
      bf16x8 pa[2];
      pa[0] = *(const bf16x8*)&Plds[(lrow) * 72 + ks * 32 + lk];
      pa[1] = *(const bf16x8*)&Plds[(16 + lrow) * 72 + ks * 32 + lk];
#pragma unroll
      for (int nf = 0; nf < 4; ++nf) {
        const bf16x8 vb = *(const bf16x8*)&Vt[((size_t)b * 256 + wid * 64 + nf * 16 + lrow) * 4096 + kb + ks * 32 + lk];
        oacc[0][nf] = __builtin_amdgcn_mfma_f32_16x16x32_bf16(pa[0], vb, oacc[0][nf], 0, 0, 0);
        oacc[1][nf] = __builtin_amdgcn_mfma_f32_16x16x32_bf16(pa[1], vb, oacc[1][nf], 0, 0, 0);
      }
    }
    __syncthreads();
  }

#pragma unroll
  for (int mf = 0; mf < 2; ++mf) {
    float* obase = out + ((size_t)b * 4096 + qb + mf * 16 + lkg * 4) * 256 + wid * 64 + lrow;
#pragma unroll
    for (int nf = 0; nf < 4; ++nf)
#pragma unroll
      for (int r = 0; r < 4; ++r)
        obase[(size_t)r * 256 + nf * 16] = oacc[mf][nf][r];
  }
}

extern "C" void kernel_launch(void* const* d_in, const int* in_sizes, int n_in,
                              void* d_out, int out_size, void* d_ws, size_t ws_size,
                              hipStream_t stream) {
  const float* x  = (const float*)d_in[0];
  const float* wq = (const float*)d_in[1];
  const float* wk = (const float*)d_in[2];
  const float* wv = (const float*)d_in[3];
  float* out = (float*)d_out;
  char* ws = (char*)d_ws;
  u16* Xb = (u16*)(ws);                          // 16384*1024*2 = 33,554,432
  u16* Wb = (u16*)(ws + (size_t)33554432);       //   768*1024*2 =  1,572,864
  u16* Qb = (u16*)(ws + (size_t)35127296);       // 16384*256*2  =  8,388,608
  u16* Kb = (u16*)(ws + (size_t)43515904);       //  8,388,608
  u16* Vt = (u16*)(ws + (size_t)51904512);       //  8,388,608  (end 60,293,120)

  hipLaunchKernelGGL(cvt_x_kernel, dim3(2048), dim3(256), 0, stream,
                     (const float4*)x, (u16x4*)Xb, 4194304);
  hipLaunchKernelGGL(cvt_w_kernel, dim3(768), dim3(256), 0, stream,
                     (const float4*)wq, (const float4*)wk, (const float4*)wv, (u16x4*)Wb);
  hipLaunchKernelGGL(qkv_gemm_kernel, dim3(256), dim3(512), 0, stream, Xb, Wb, Qb, Kb, Vt);
  hipLaunchKernelGGL(attn_kernel, dim3(512), dim3(256), 0, stream, Qb, Kb, Vt, out);
}